// Round 1
// baseline (113.765 us; speedup 1.0000x reference)
//
#include <hip/hip_runtime.h>

// Chamfer-style point loss: B=16, N=4096, F=3, fp32.
// min_j ||x - y_j||^2 = sqx - 2 * max_j ( x . y_j - sqy_j/2 )
// Pack points as float4(x, y, z, -0.5*sq) so inner loop is 3 fma + 1 max.

constexpr int B_ = 16;
constexpr int N_ = 4096;
constexpr int BN = B_ * N_;          // 65536
constexpr int JSPLIT = 2;            // j-range split per direction
constexpr int IPT = 2;               // points (i) per thread
constexpr int BLK = 256;
constexpr int ICHUNK = BLK * IPT;    // 512 i's per block
constexpr int JCHUNK = N_ / JSPLIT;  // 2048

__global__ __launch_bounds__(BLK)
void prep_kernel(const float* __restrict__ a1, const float* __restrict__ a2,
                 float4* __restrict__ P1, float4* __restrict__ P2) {
    int gi = blockIdx.x * BLK + threadIdx.x;           // [0, BN)
    const float* in = blockIdx.y ? a2 : a1;
    float4* out = blockIdx.y ? P2 : P1;
    float x = in[3 * gi], y = in[3 * gi + 1], z = in[3 * gi + 2];
    out[gi] = make_float4(x, y, z, -0.5f * fmaf(x, x, fmaf(y, y, z * z)));
}

// grid: (N/ICHUNK=8, B=16, 4)  z = d*2 + s  (d = direction, s = j-split)
__global__ __launch_bounds__(BLK)
void minmax_kernel(const float4* __restrict__ P1, const float4* __restrict__ P2,
                   float* __restrict__ pm) {
    int b = blockIdx.y;
    int z = blockIdx.z;
    int d = z >> 1, s = z & 1;
    const float4* __restrict__ PX = d ? P2 : P1;
    const float4* __restrict__ PY = d ? P1 : P2;

    int base = blockIdx.x * ICHUNK + threadIdx.x;      // i within row
    float4 xa = PX[b * N_ + base];
    float4 xb = PX[b * N_ + base + BLK];
    const float4* __restrict__ Yrow = PY + b * N_ + s * JCHUNK;

    float ma = -3.0e38f, mb = -3.0e38f;
#pragma unroll 8
    for (int j = 0; j < JCHUNK; ++j) {
        float4 w = Yrow[j];                            // wave-uniform 16B load
        float ca = fmaf(xa.x, w.x, fmaf(xa.y, w.y, fmaf(xa.z, w.z, w.w)));
        float cb = fmaf(xb.x, w.x, fmaf(xb.y, w.y, fmaf(xb.z, w.z, w.w)));
        ma = fmaxf(ma, ca);
        mb = fmaxf(mb, cb);
    }
    int o = z * BN + b * N_ + base;                    // pm[z][b*N + i]
    pm[o] = ma;
    pm[o + BLK] = mb;
}

__device__ inline float block_sum_256(float v, float* red4) {
    for (int off = 32; off; off >>= 1) v += __shfl_down(v, off, 64);
    int lane = threadIdx.x & 63, w = threadIdx.x >> 6;
    if (lane == 0) red4[w] = v;
    __syncthreads();
    return red4[0] + red4[1] + red4[2] + red4[3];      // valid for all after sync
}

// grid: 256 blocks * 256 threads == BN, each thread handles one gi for both dirs
__global__ __launch_bounds__(BLK)
void reduce1_kernel(const float4* __restrict__ P1, const float4* __restrict__ P2,
                    const float* __restrict__ pm, float* __restrict__ sums) {
    int t = blockIdx.x * BLK + threadIdx.x;
    float m0 = fmaxf(pm[t], pm[BN + t]);               // d=0 (X=array1)
    float m1 = fmaxf(pm[2 * BN + t], pm[3 * BN + t]);  // d=1 (X=array2)
    float v = -2.0f * (P1[t].w + m0) - 2.0f * (P2[t].w + m1);
    __shared__ float red4[4];
    float s = block_sum_256(v, red4);
    if (threadIdx.x == 0) sums[blockIdx.x] = s;
}

__global__ __launch_bounds__(BLK)
void reduce2_kernel(const float* __restrict__ sums, float* __restrict__ out) {
    float v = sums[threadIdx.x];
    __shared__ float red4[4];
    float s = block_sum_256(v, red4);
    if (threadIdx.x == 0) out[0] = s * (50.0f / (float)BN);
}

extern "C" void kernel_launch(void* const* d_in, const int* in_sizes, int n_in,
                              void* d_out, int out_size, void* d_ws, size_t ws_size,
                              hipStream_t stream) {
    const float* a1 = (const float*)d_in[0];
    const float* a2 = (const float*)d_in[1];
    char* ws = (char*)d_ws;
    float4* P1 = (float4*)(ws);                        // 1 MB
    float4* P2 = (float4*)(ws + (1u << 20));           // 1 MB
    float* pm = (float*)(ws + (2u << 20));             // 4*BN*4 = 1 MB
    float* sums = (float*)(ws + (3u << 20));           // 1 KB
    float* out = (float*)d_out;

    prep_kernel<<<dim3(BN / BLK, 2), BLK, 0, stream>>>(a1, a2, P1, P2);
    minmax_kernel<<<dim3(N_ / ICHUNK, B_, 2 * JSPLIT), BLK, 0, stream>>>(P1, P2, pm);
    reduce1_kernel<<<dim3(BN / BLK), BLK, 0, stream>>>(P1, P2, pm, sums);
    reduce2_kernel<<<dim3(1), BLK, 0, stream>>>(sums, out);
}

// Round 2
// 76.773 us; speedup vs baseline: 1.4818x; 1.4818x over previous
//
#include <hip/hip_runtime.h>

// Chamfer-style point loss: B=16, N=4096, F=3, fp32.
// min_j ||x - y_j||^2 = sqx - 2 * max_j ( x . y_j - sqy_j/2 )
// Pack points as float4(x, y, z, -0.5*sq) so inner loop is 3 fma + 1 max per pair.

constexpr int B_ = 16;
constexpr int N_ = 4096;
constexpr int BN = B_ * N_;          // 65536
constexpr int JSPLIT = 8;            // j-range split per direction
constexpr int IPT = 4;               // points (i) per thread
constexpr int BLK = 256;
constexpr int ICHUNK = BLK * IPT;    // 1024 i's per block
constexpr int JCHUNK = N_ / JSPLIT;  // 512

__global__ __launch_bounds__(BLK)
void prep_kernel(const float* __restrict__ a1, const float* __restrict__ a2,
                 float4* __restrict__ P1, float4* __restrict__ P2) {
    int gi = blockIdx.x * BLK + threadIdx.x;           // [0, BN)
    const float* in = blockIdx.y ? a2 : a1;
    float4* out = blockIdx.y ? P2 : P1;
    float x = in[3 * gi], y = in[3 * gi + 1], z = in[3 * gi + 2];
    out[gi] = make_float4(x, y, z, -0.5f * fmaf(x, x, fmaf(y, y, z * z)));
}

// grid: (N/ICHUNK=4, B=16, 2*JSPLIT=16)  z = d*JSPLIT + s  (d = direction)
__global__ __launch_bounds__(BLK, 4)
void minmax_kernel(const float4* __restrict__ P1, const float4* __restrict__ P2,
                   float* __restrict__ pm) {
    int b = blockIdx.y;
    int z = blockIdx.z;
    int d = z >> 3, s = z & 7;
    const float4* __restrict__ PX = d ? P2 : P1;
    const float4* __restrict__ PY = d ? P1 : P2;

    int base = blockIdx.x * ICHUNK + threadIdx.x;      // i within row
    float4 x0 = PX[b * N_ + base];
    float4 x1 = PX[b * N_ + base + BLK];
    float4 x2 = PX[b * N_ + base + 2 * BLK];
    float4 x3 = PX[b * N_ + base + 3 * BLK];
    const float4* __restrict__ Yrow = PY + b * N_ + s * JCHUNK;

    float m0 = -3.0e38f, m1 = -3.0e38f, m2 = -3.0e38f, m3 = -3.0e38f;
#pragma unroll 8
    for (int j = 0; j < JCHUNK; ++j) {
        float4 w = Yrow[j];                            // wave-uniform 16B load (L1-hit)
        m0 = fmaxf(m0, fmaf(x0.x, w.x, fmaf(x0.y, w.y, fmaf(x0.z, w.z, w.w))));
        m1 = fmaxf(m1, fmaf(x1.x, w.x, fmaf(x1.y, w.y, fmaf(x1.z, w.z, w.w))));
        m2 = fmaxf(m2, fmaf(x2.x, w.x, fmaf(x2.y, w.y, fmaf(x2.z, w.z, w.w))));
        m3 = fmaxf(m3, fmaf(x3.x, w.x, fmaf(x3.y, w.y, fmaf(x3.z, w.z, w.w))));
    }
    int o = z * BN + b * N_ + base;                    // pm[z][b*N + i]
    pm[o] = m0;
    pm[o + BLK] = m1;
    pm[o + 2 * BLK] = m2;
    pm[o + 3 * BLK] = m3;
}

__device__ inline float block_sum_256(float v, float* red4) {
    for (int off = 32; off; off >>= 1) v += __shfl_down(v, off, 64);
    int lane = threadIdx.x & 63, w = threadIdx.x >> 6;
    if (lane == 0) red4[w] = v;
    __syncthreads();
    return red4[0] + red4[1] + red4[2] + red4[3];      // valid for all after sync
}

// grid: 256 blocks * 256 threads == BN, each thread handles one gi for both dirs
__global__ __launch_bounds__(BLK)
void reduce1_kernel(const float4* __restrict__ P1, const float4* __restrict__ P2,
                    const float* __restrict__ pm, float* __restrict__ sums) {
    int t = blockIdx.x * BLK + threadIdx.x;
    float m0 = -3.0e38f, m1 = -3.0e38f;
#pragma unroll
    for (int s = 0; s < JSPLIT; ++s) {
        m0 = fmaxf(m0, pm[s * BN + t]);                        // d=0 (X=array1)
        m1 = fmaxf(m1, pm[(JSPLIT + s) * BN + t]);             // d=1 (X=array2)
    }
    float v = -2.0f * (P1[t].w + m0) - 2.0f * (P2[t].w + m1);
    __shared__ float red4[4];
    float s = block_sum_256(v, red4);
    if (threadIdx.x == 0) sums[blockIdx.x] = s;
}

__global__ __launch_bounds__(BLK)
void reduce2_kernel(const float* __restrict__ sums, float* __restrict__ out) {
    float v = sums[threadIdx.x];
    __shared__ float red4[4];
    float s = block_sum_256(v, red4);
    if (threadIdx.x == 0) out[0] = s * (50.0f / (float)BN);
}

extern "C" void kernel_launch(void* const* d_in, const int* in_sizes, int n_in,
                              void* d_out, int out_size, void* d_ws, size_t ws_size,
                              hipStream_t stream) {
    const float* a1 = (const float*)d_in[0];
    const float* a2 = (const float*)d_in[1];
    char* ws = (char*)d_ws;
    float4* P1 = (float4*)(ws);                        // 1 MB
    float4* P2 = (float4*)(ws + (1u << 20));           // 1 MB
    float* pm = (float*)(ws + (2u << 20));             // 2*JSPLIT*BN*4 = 4 MB
    float* sums = (float*)(ws + (6u << 20));           // 1 KB
    float* out = (float*)d_out;

    prep_kernel<<<dim3(BN / BLK, 2), BLK, 0, stream>>>(a1, a2, P1, P2);
    minmax_kernel<<<dim3(N_ / ICHUNK, B_, 2 * JSPLIT), BLK, 0, stream>>>(P1, P2, pm);
    reduce1_kernel<<<dim3(BN / BLK), BLK, 0, stream>>>(P1, P2, pm, sums);
    reduce2_kernel<<<dim3(1), BLK, 0, stream>>>(sums, out);
}

// Round 4
// 75.751 us; speedup vs baseline: 1.5018x; 1.0135x over previous
//
#include <hip/hip_runtime.h>

// Chamfer-style point loss: B=16, N=4096, F=3, fp32.
// min_j ||x - y_j||^2 = sqx - 2 * max_j ( x . y_j - sqy_j/2 )
// Pack points as float4(x, y, z, -0.5*sq): inner loop is 3 fma + 1 max per pair.

constexpr int B_ = 16;
constexpr int N_ = 4096;
constexpr int BN = B_ * N_;          // 65536
constexpr int JSPLIT = 16;           // j-range split per direction
constexpr int IPT = 4;               // points (i) per thread
constexpr int BLK = 256;
constexpr int ICHUNK = BLK * IPT;    // 1024 i's per block
constexpr int JCHUNK = N_ / JSPLIT;  // 256

__global__ __launch_bounds__(BLK)
void prep_kernel(const float* __restrict__ a1, const float* __restrict__ a2,
                 float4* __restrict__ P1, float4* __restrict__ P2) {
    int gi = blockIdx.x * BLK + threadIdx.x;           // [0, BN)
    const float* in = blockIdx.y ? a2 : a1;
    float4* out = blockIdx.y ? P2 : P1;
    float x = in[3 * gi], y = in[3 * gi + 1], z = in[3 * gi + 2];
    out[gi] = make_float4(x, y, z, -0.5f * fmaf(x, x, fmaf(y, y, z * z)));
}

// NOTE: parameter named W (capital) — lowercase w collides with the .w member
// under preprocessor substitution.
#define STEP(W)                                                                     \
    m0 = fmaxf(m0, fmaf(x0.x, (W).x, fmaf(x0.y, (W).y, fmaf(x0.z, (W).z, (W).w)))); \
    m1 = fmaxf(m1, fmaf(x1.x, (W).x, fmaf(x1.y, (W).y, fmaf(x1.z, (W).z, (W).w)))); \
    m2 = fmaxf(m2, fmaf(x2.x, (W).x, fmaf(x2.y, (W).y, fmaf(x2.z, (W).z, (W).w)))); \
    m3 = fmaxf(m3, fmaf(x3.x, (W).x, fmaf(x3.y, (W).y, fmaf(x3.z, (W).z, (W).w))));

// grid: (N/ICHUNK=4, B=16, 2*JSPLIT=32)  z = d*JSPLIT + s  (d = direction)
// 2048 blocks = 8 blocks/CU = 8 waves/SIMD.
__global__ __launch_bounds__(BLK, 8)
void minmax_kernel(const float4* __restrict__ P1, const float4* __restrict__ P2,
                   float* __restrict__ pm) {
    int b = blockIdx.y;
    int z = blockIdx.z;
    int d = z >> 4, s = z & 15;
    const float4* __restrict__ PX = d ? P2 : P1;
    const float4* __restrict__ PY = d ? P1 : P2;

    int base = blockIdx.x * ICHUNK + threadIdx.x;      // i within row
    float4 x0 = PX[b * N_ + base];
    float4 x1 = PX[b * N_ + base + BLK];
    float4 x2 = PX[b * N_ + base + 2 * BLK];
    float4 x3 = PX[b * N_ + base + 3 * BLK];
    const float4* __restrict__ Yrow = PY + b * N_ + s * JCHUNK;

    float m0 = -3.0e38f, m1 = -3.0e38f, m2 = -3.0e38f, m3 = -3.0e38f;

    // Explicit software pipeline: next 4 wave-uniform loads in flight while
    // computing on the previous 4 (64 VALU instrs of cover per iteration).
    float4 w0 = Yrow[0], w1 = Yrow[1], w2 = Yrow[2], w3 = Yrow[3];
#pragma unroll 1
    for (int j = 0; j < JCHUNK - 4; j += 4) {
        float4 n0 = Yrow[j + 4], n1 = Yrow[j + 5], n2 = Yrow[j + 6], n3 = Yrow[j + 7];
        STEP(w0) STEP(w1) STEP(w2) STEP(w3)
        w0 = n0; w1 = n1; w2 = n2; w3 = n3;
    }
    STEP(w0) STEP(w1) STEP(w2) STEP(w3)

    int o = z * BN + b * N_ + base;                    // pm[z][b*N + i]
    pm[o] = m0;
    pm[o + BLK] = m1;
    pm[o + 2 * BLK] = m2;
    pm[o + 3 * BLK] = m3;
}

__device__ inline float block_sum_256(float v, float* red4) {
    for (int off = 32; off; off >>= 1) v += __shfl_down(v, off, 64);
    int lane = threadIdx.x & 63, w = threadIdx.x >> 6;
    if (lane == 0) red4[w] = v;
    __syncthreads();
    return red4[0] + red4[1] + red4[2] + red4[3];      // valid for all after sync
}

// grid: 256 blocks * 256 threads == BN, each thread handles one gi for both dirs
__global__ __launch_bounds__(BLK)
void reduce1_kernel(const float4* __restrict__ P1, const float4* __restrict__ P2,
                    const float* __restrict__ pm, float* __restrict__ sums) {
    int t = blockIdx.x * BLK + threadIdx.x;
    float m0 = -3.0e38f, m1 = -3.0e38f;
#pragma unroll
    for (int s = 0; s < JSPLIT; ++s) {
        m0 = fmaxf(m0, pm[s * BN + t]);                        // d=0 (X=array1)
        m1 = fmaxf(m1, pm[(JSPLIT + s) * BN + t]);             // d=1 (X=array2)
    }
    float v = -2.0f * (P1[t].w + m0) - 2.0f * (P2[t].w + m1);
    __shared__ float red4[4];
    float s = block_sum_256(v, red4);
    if (threadIdx.x == 0) sums[blockIdx.x] = s;
}

__global__ __launch_bounds__(BLK)
void reduce2_kernel(const float* __restrict__ sums, float* __restrict__ out) {
    float v = sums[threadIdx.x];
    __shared__ float red4[4];
    float s = block_sum_256(v, red4);
    if (threadIdx.x == 0) out[0] = s * (50.0f / (float)BN);
}

extern "C" void kernel_launch(void* const* d_in, const int* in_sizes, int n_in,
                              void* d_out, int out_size, void* d_ws, size_t ws_size,
                              hipStream_t stream) {
    const float* a1 = (const float*)d_in[0];
    const float* a2 = (const float*)d_in[1];
    char* ws = (char*)d_ws;
    float4* P1 = (float4*)(ws);                        // 1 MB
    float4* P2 = (float4*)(ws + (1u << 20));           // 1 MB
    float* pm = (float*)(ws + (2u << 20));             // 2*JSPLIT*BN*4 = 8 MB
    float* sums = (float*)(ws + (10u << 20));          // 1 KB
    float* out = (float*)d_out;

    prep_kernel<<<dim3(BN / BLK, 2), BLK, 0, stream>>>(a1, a2, P1, P2);
    minmax_kernel<<<dim3(N_ / ICHUNK, B_, 2 * JSPLIT), BLK, 0, stream>>>(P1, P2, pm);
    reduce1_kernel<<<dim3(BN / BLK), BLK, 0, stream>>>(P1, P2, pm, sums);
    reduce2_kernel<<<dim3(1), BLK, 0, stream>>>(sums, out);
}

// Round 5
// 47.014 us; speedup vs baseline: 2.4198x; 1.6113x over previous
//
#include <hip/hip_runtime.h>

// Chamfer-style point loss via MFMA: B=16, N=4096, F=3, fp32 accuracy via
// bf16 hi/lo split. Element(i,j) = x_i.y_j - sqx_i/2 - sqy_j/2 = -D_ij/2,
// so min_j D_i = -2 * max_j elem. Both sq terms folded into the MFMA K-dim
// => the summed result is invariant to any fragment-layout transposition.

constexpr int B_ = 16;
constexpr int N_ = 4096;
constexpr int BN = B_ * N_;          // 65536
constexpr int BLK = 256;
constexpr int JTILES = N_ / 16;      // 256

using bf16x8 = __attribute__((ext_vector_type(8))) __bf16;
using f32x4  = __attribute__((ext_vector_type(4))) float;

__device__ inline uint bf16_rne(float f) {
    uint u = __float_as_uint(f);
    return (u + 0x7FFFu + ((u >> 16) & 1u)) >> 16;
}
__device__ inline float bf16_f(uint h) { return __uint_as_float(h << 16); }

// K-slot packing (16 bf16 = 32B per point, per role):
// A-row (X): [hx,hy,hz, lx,ly,lz, hx,hy | hz, 1, 1, thx, tlx, 0,0,0]
// B-col (Y): [hx,hy,hz, hx,hy,hz, lx,ly | lz, thy, tly, 1, 1, 0,0,0]
// Sum_k A[k]B[k] = hi.hi + lo.hi + hi.lo + t_y + t_x,  t = -sq/2 (hi/lo split)
__global__ __launch_bounds__(BLK)
void prep_kernel(const float* __restrict__ a1, const float* __restrict__ a2,
                 uint4* __restrict__ A1, uint4* __restrict__ B1,
                 uint4* __restrict__ A2, uint4* __restrict__ B2) {
    int gi = blockIdx.x * BLK + threadIdx.x;           // [0, BN)
    const float* in = blockIdx.y ? a2 : a1;
    uint4* Ao = blockIdx.y ? A2 : A1;
    uint4* Bo = blockIdx.y ? B2 : B1;
    float x = in[3 * gi], y = in[3 * gi + 1], z = in[3 * gi + 2];
    float sq = fmaf(x, x, fmaf(y, y, z * z));
    float t = -0.5f * sq;
    uint hx = bf16_rne(x), hy = bf16_rne(y), hz = bf16_rne(z);
    uint lx = bf16_rne(x - bf16_f(hx));
    uint ly = bf16_rne(y - bf16_f(hy));
    uint lz = bf16_rne(z - bf16_f(hz));
    uint th = bf16_rne(t);
    uint tl = bf16_rne(t - bf16_f(th));
    const uint ONE = 0x3F80u;
    Ao[2 * gi]     = make_uint4(hx | (hy << 16), hz | (lx << 16), ly | (lz << 16), hx | (hy << 16));
    Ao[2 * gi + 1] = make_uint4(hz | (ONE << 16), ONE | (th << 16), tl, 0u);
    Bo[2 * gi]     = make_uint4(hx | (hy << 16), hz | (hx << 16), hy | (hz << 16), lx | (ly << 16));
    Bo[2 * gi + 1] = make_uint4(lz | (th << 16), tl | (ONE << 16), ONE, 0u);
}

#define CSTEP(P_) {                                                            \
    f32x4 o0 = __builtin_amdgcn_mfma_f32_16x16x32_bf16(a0, (P_), cz, 0, 0, 0); \
    f32x4 o1 = __builtin_amdgcn_mfma_f32_16x16x32_bf16(a1, (P_), cz, 0, 0, 0); \
    vm0[0] = fmaxf(vm0[0], o0[0]); vm0[1] = fmaxf(vm0[1], o0[1]);              \
    vm0[2] = fmaxf(vm0[2], o0[2]); vm0[3] = fmaxf(vm0[3], o0[3]);              \
    vm1[0] = fmaxf(vm1[0], o1[0]); vm1[1] = fmaxf(vm1[1], o1[1]);              \
    vm1[2] = fmaxf(vm1[2], o1[2]); vm1[3] = fmaxf(vm1[3], o1[3]); }

// grid: (N/128=32, B=16, 2). Block = 4 waves x 2 i-tiles = 128 i's, all 4096 j's.
__global__ __launch_bounds__(BLK, 4)
void minmax_kernel(const uint4* __restrict__ A1u, const uint4* __restrict__ B1u,
                   const uint4* __restrict__ A2u, const uint4* __restrict__ B2u,
                   float* __restrict__ vout) {
    int d = blockIdx.z, b = blockIdx.y;
    const bf16x8* __restrict__ Aarr = (const bf16x8*)(d ? A2u : A1u);
    const bf16x8* __restrict__ Barr = (const bf16x8*)(d ? B1u : B2u);
    int tid = threadIdx.x;
    int L = tid & 63, w = tid >> 6;
    int lpt = L & 15, hi = (L >> 4) & 1;
    bool act = L < 32;                                 // k-groups 2,3 are zero
    int ibase = blockIdx.x * 128 + w * 32;             // i within batch row

    const bf16x8* pA = Aarr + (size_t)(b * N_ + ibase + lpt) * 2 + hi;
    const bf16x8* pB = Barr + (size_t)(b * N_ + lpt) * 2 + hi;

    uint4 zu; zu.x = zu.y = zu.z = zu.w = 0u;
    bf16x8 zf = __builtin_bit_cast(bf16x8, zu);
    bf16x8 a0 = act ? pA[0] : zf;                      // i-tile 0
    bf16x8 a1 = act ? pA[32] : zf;                     // i-tile 1 (+16 pts * 2)
    f32x4 cz = {0.f, 0.f, 0.f, 0.f};
    f32x4 vm0 = {-3.0e38f, -3.0e38f, -3.0e38f, -3.0e38f};
    f32x4 vm1 = vm0;

    // group-of-4 software pipeline; B loads are unconditional (lanes>=32 read
    // duplicate valid addresses; their A-side zeros kill the products).
    bf16x8 p0 = pB[0], p1 = pB[32], p2 = pB[64], p3 = pB[96];
#pragma unroll 1
    for (int jt = 0; jt < JTILES - 4; jt += 4) {
        bf16x8 n0 = pB[(size_t)(jt + 4) * 32], n1 = pB[(size_t)(jt + 5) * 32];
        bf16x8 n2 = pB[(size_t)(jt + 6) * 32], n3 = pB[(size_t)(jt + 7) * 32];
        CSTEP(p0) CSTEP(p1) CSTEP(p2) CSTEP(p3)
        p0 = n0; p1 = n1; p2 = n2; p3 = n3;
    }
    CSTEP(p0) CSTEP(p1) CSTEP(p2) CSTEP(p3)

    // butterfly max across the 16 "col" lanes (within row-group)
#pragma unroll
    for (int off = 1; off < 16; off <<= 1) {
#pragma unroll
        for (int r = 0; r < 4; ++r) {
            vm0[r] = fmaxf(vm0[r], __shfl_xor(vm0[r], off));
            vm1[r] = fmaxf(vm1[r], __shfl_xor(vm1[r], off));
        }
    }
    if (lpt == 0) {
        int rg = L >> 4;                               // 0..3
#pragma unroll
        for (int r = 0; r < 4; ++r) {
            int row = rg * 4 + r;                      // 0..15 within tile
            int o = d * BN + b * N_ + ibase + row;
            vout[o] = -2.0f * vm0[r];
            vout[o + 16] = -2.0f * vm1[r];
        }
    }
}

__device__ inline float block_sum_256(float v, float* red4) {
    for (int off = 32; off; off >>= 1) v += __shfl_down(v, off, 64);
    int lane = threadIdx.x & 63, w = threadIdx.x >> 6;
    if (lane == 0) red4[w] = v;
    __syncthreads();
    return red4[0] + red4[1] + red4[2] + red4[3];
}

__global__ __launch_bounds__(BLK)
void reduce1_kernel(const float* __restrict__ vout, float* __restrict__ sums) {
    int t = blockIdx.x * BLK + threadIdx.x;
    float v = vout[t] + vout[BN + t];
    __shared__ float red4[4];
    float s = block_sum_256(v, red4);
    if (threadIdx.x == 0) sums[blockIdx.x] = s;
}

__global__ __launch_bounds__(BLK)
void reduce2_kernel(const float* __restrict__ sums, float* __restrict__ out) {
    float v = sums[threadIdx.x];
    __shared__ float red4[4];
    float s = block_sum_256(v, red4);
    if (threadIdx.x == 0) out[0] = s * (50.0f / (float)BN);
}

extern "C" void kernel_launch(void* const* d_in, const int* in_sizes, int n_in,
                              void* d_out, int out_size, void* d_ws, size_t ws_size,
                              hipStream_t stream) {
    const float* a1 = (const float*)d_in[0];
    const float* a2 = (const float*)d_in[1];
    char* ws = (char*)d_ws;
    uint4* A1 = (uint4*)(ws);                          // 2 MB each
    uint4* B1 = (uint4*)(ws + (2u << 20));
    uint4* A2 = (uint4*)(ws + (4u << 20));
    uint4* B2 = (uint4*)(ws + (6u << 20));
    float* vout = (float*)(ws + (8u << 20));           // 512 KB
    float* sums = (float*)(ws + (8u << 20) + (512u << 10));
    float* out = (float*)d_out;

    prep_kernel<<<dim3(BN / BLK, 2), BLK, 0, stream>>>(a1, a2, A1, B1, A2, B2);
    minmax_kernel<<<dim3(N_ / 128, B_, 2), BLK, 0, stream>>>(A1, B1, A2, B2, vout);
    reduce1_kernel<<<dim3(BN / BLK), BLK, 0, stream>>>(vout, sums);
    reduce2_kernel<<<dim3(1), BLK, 0, stream>>>(sums, out);
}